// Round 8
// baseline (270.782 us; speedup 1.0000x reference)
//
#include <hip/hip_runtime.h>
#include <hip/hip_bf16.h>

// SplineConv K=2:  out = relu( (S/deg)@W0 + (A1/deg)@(W1-W0) + x@root + bias )
// S[n] = sum_{e->n} x[src_e],  A1[n] = sum_{e->n} v_e x[src_e].
//
// R2: f32-atomic scatter = TCC atomic-ALU bound (541us).
// R3: 2-node f32 gemm spilled (VGPR 256, 2610us).
// R4: 301us = fill 92 + gather 92 + gemm_q 90 (LDS-read-bound).
// R5/R7: 249/244us; fill ~88us pinned: 4B-vs-8B entries changed nothing ->
//     scattered-LINE-transaction bound (1.2M random atomics + 1.2M random
//     stores, cross-XCD partial-line writebacks, ~900cy/miss).
// R8: bin-granular partition (8 XCD-split sub-cursors per 96-node bin,
//     frontier lines single-XCD -> L2-merged) + per-bin LDS counting sort
//     fused into gather. Global per-node bucket eliminated entirely.

#define CH 64
#define CAP 64      // fallback-path bucket cap
#define BINSZ 96    // nodes per bin
#define NSUB 8      // sub-cursors per bin (blockIdx&7 ~ XCD)
#define SUBCAP 256  // records per sub-cursor; mean 144, 9.3 sigma headroom
#define LCAP (NSUB * SUBCAP)  // 2048 records max per bin

typedef __attribute__((ext_vector_type(8))) short bf16x8;
typedef __attribute__((ext_vector_type(4))) float f32x4;
typedef __attribute__((ext_vector_type(8))) unsigned short u16x8;

static __device__ __forceinline__ unsigned short f2bu(float f) {
  __hip_bfloat16 h = __float2bfloat16(f);  // RTN
  return *(unsigned short*)&h;
}
static __device__ __forceinline__ float bu2f(unsigned short u) {
  return __uint_as_float(((unsigned)u) << 16);
}

// ---------- combined weight M^T bf16 [64][192] ----------
__global__ __launch_bounds__(256) void build_M(
    const float* __restrict__ W, const float* __restrict__ root,
    unsigned short* __restrict__ Mb) {
  int idx = blockIdx.x * 256 + threadIdx.x;
  if (idx >= 192 * 64) return;
  int k = idx >> 6, o = idx & 63;
  float val;
  if (k < 64)       val = W[k * 64 + o];
  else if (k < 128) val = W[4096 + (k - 64) * 64 + o] - W[(k - 64) * 64 + o];
  else              val = root[(k - 128) * 64 + o];
  Mb[o * 192 + k] = f2bu(val);
}

// ---------- fused: x->bf16 cast (blocks [0,castBlocks)) + edge partition ----------
__global__ __launch_bounds__(256) void partition_cast(
    const float* __restrict__ x, unsigned short* __restrict__ xb,
    int castTotal, int castBlocks,
    const int* __restrict__ ei, const float* __restrict__ attr,
    int* __restrict__ cnt8, uint2* __restrict__ rec, int E) {
  if ((int)blockIdx.x < castBlocks) {
    int i = (blockIdx.x * 256 + threadIdx.x) * 8;
    if (i >= castTotal) return;
    const float4* p = (const float4*)(x + i);
    float4 a = p[0], b = p[1];
    u16x8 o;
    o[0] = f2bu(a.x); o[1] = f2bu(a.y); o[2] = f2bu(a.z); o[3] = f2bu(a.w);
    o[4] = f2bu(b.x); o[5] = f2bu(b.y); o[6] = f2bu(b.z); o[7] = f2bu(b.w);
    *(u16x8*)(xb + i) = o;
    return;
  }
  int e = (blockIdx.x - castBlocks) * 256 + threadIdx.x;
  if (e >= E) return;
  int src = ei[e];
  int dst = ei[E + e];
  float v = attr[e];
  unsigned enc = ((unsigned)src << 15) | (unsigned)(v * 32767.0f + 0.5f);
  unsigned bin = (unsigned)dst / BINSZ;
  unsigned dloc = (unsigned)dst - bin * BINSZ;
  int slot = bin * NSUB + (blockIdx.x & 7);  // blockIdx&7 ~ XCD: frontier lines stay local
  int pos = atomicAdd(&cnt8[slot], 1);
  if (pos < SUBCAP) rec[(size_t)slot * SUBCAP + pos] = make_uint2(enc, dloc);
}

// ---------- per-bin: stage -> LDS counting sort -> register gather ----------
__global__ __launch_bounds__(256) void gather_sort(
    const unsigned short* __restrict__ xb, const int* __restrict__ cnt8,
    const uint2* __restrict__ rec, unsigned short* __restrict__ Sb,
    unsigned short* __restrict__ Ab, int n) {
  __shared__ uint2 lrec[LCAP];            // 16KB
  __shared__ unsigned short sidx[LCAP];   // 4KB
  __shared__ int hist[BINSZ], off[BINSZ], cur[BINSZ];
  __shared__ int chunkoff[NSUB + 1];
  int bin = blockIdx.x;
  int t = threadIdx.x;

  if (t == 0) {
    int s = 0;
    for (int k = 0; k < NSUB; ++k) {
      chunkoff[k] = s;
      int c = cnt8[bin * NSUB + k];
      s += (c > SUBCAP ? SUBCAP : c);
    }
    chunkoff[NSUB] = s;
  }
  for (int i = t; i < BINSZ; i += 256) hist[i] = 0;
  __syncthreads();
  int tot = chunkoff[NSUB];

  // stage this bin's records (coalesced per chunk)
  for (int k = 0; k < NSUB; ++k) {
    int base = chunkoff[k], len = chunkoff[k + 1] - base;
    for (int i = t; i < len; i += 256)
      lrec[base + i] = rec[(size_t)(bin * NSUB + k) * SUBCAP + i];
  }
  __syncthreads();
  // histogram over local node id
  for (int i = t; i < tot; i += 256) atomicAdd(&hist[lrec[i].y], 1);
  __syncthreads();
  if (t == 0) {
    int s = 0;
    for (int d = 0; d < BINSZ; ++d) { off[d] = s; cur[d] = s; s += hist[d]; }
  }
  __syncthreads();
  // scatter sort indices
  for (int i = t; i < tot; i += 256) {
    int p = atomicAdd(&cur[lrec[i].y], 1);
    sidx[p] = (unsigned short)i;
  }
  __syncthreads();

  // per-node gather: wave w handles local nodes w, w+4, ...
  int wv = t >> 6, lane = t & 63;
  int nlocal = n - bin * BINSZ;
  if (nlocal > BINSZ) nlocal = BINSZ;
  for (int d = wv; d < nlocal; d += 4) {
    int deg = hist[d], base = off[d];
    float s = 0.0f, a = 0.0f;
    for (int j = 0; j < deg; j += 16) {
      unsigned short xr[16];
      unsigned ee[16];
#pragma unroll
      for (int u = 0; u < 16; ++u) {
        int jj = j + u;
        bool val = jj < deg;                    // wave-uniform
        int idx = base + (val ? jj : 0);        // always in-bounds (deg>0 here)
        unsigned e = lrec[sidx[idx]].x;         // LDS broadcast
        ee[u] = val ? e : 0u;
        int srcj = val ? (int)(e >> 15) : 0;
        xr[u] = xb[(size_t)srcj * CH + lane];   // 16 independent 128B gathers
      }
#pragma unroll
      for (int u = 0; u < 16; ++u) {
        float w = (j + u < deg) ? 1.0f : 0.0f;
        float xv = bu2f(xr[u]);
        float vv = (float)(ee[u] & 32767u) * (1.0f / 32767.0f);
        s = fmaf(w, xv, s);
        a = fmaf(w * vv, xv, a);
      }
    }
    int node = bin * BINSZ + d;
    float inv = 1.0f / fmaxf((float)deg, 1.0f);  // fold mean
    Sb[(size_t)node * CH + lane] = f2bu(s * inv);
    Ab[(size_t)node * CH + lane] = f2bu(a * inv);
  }
}

// ---------- fallback path (ws too small): R7 atomic scatter ----------
__global__ __launch_bounds__(256) void cast_x(
    const float* __restrict__ x, unsigned short* __restrict__ xb, int total) {
  int i = (blockIdx.x * 256 + threadIdx.x) * 8;
  if (i >= total) return;
  const float4* p = (const float4*)(x + i);
  float4 a = p[0], b = p[1];
  u16x8 o;
  o[0] = f2bu(a.x); o[1] = f2bu(a.y); o[2] = f2bu(a.z); o[3] = f2bu(a.w);
  o[4] = f2bu(b.x); o[5] = f2bu(b.y); o[6] = f2bu(b.z); o[7] = f2bu(b.w);
  *(u16x8*)(xb + i) = o;
}

__global__ __launch_bounds__(256) void spline_scatter(
    const float* __restrict__ x, const int* __restrict__ ei,
    const float* __restrict__ attr, float* __restrict__ S,
    float* __restrict__ A1, float* __restrict__ degf, int E) {
  int w = (int)((blockIdx.x * 4) + (threadIdx.x >> 6));
  int lane = threadIdx.x & 63;
  if (w >= E) return;
  int src = ei[w];
  int dst = ei[E + w];
  float v = attr[w];
  float xv = x[(size_t)src * CH + lane];
  atomicAdd(&S[(size_t)dst * CH + lane], xv);
  atomicAdd(&A1[(size_t)dst * CH + lane], v * xv);
  if (lane == 0) atomicAdd(&degf[dst], 1.0f);
}

__global__ __launch_bounds__(256) void conv_fb(
    const float* __restrict__ S, const float* __restrict__ A1,
    const float* __restrict__ degf, unsigned short* __restrict__ Sb,
    unsigned short* __restrict__ Ab, int total) {
  int i = blockIdx.x * 256 + threadIdx.x;
  if (i >= total) return;
  float inv = 1.0f / fmaxf(degf[i >> 6], 1.0f);
  Sb[i] = f2bu(S[i] * inv);
  Ab[i] = f2bu(A1[i] * inv);
}

// ---------- MFMA GEMM: B-frags in regs, 2 tiles/wave, no LDS ----------
__global__ __launch_bounds__(256) void spline_gemm_mfma(
    const unsigned short* __restrict__ Sb, const unsigned short* __restrict__ Ab,
    const unsigned short* __restrict__ Xb, const unsigned short* __restrict__ Mb,
    const float* __restrict__ bias, float* __restrict__ out, int n, int ntiles) {
  int t = threadIdx.x;
  int lane = t & 63;
  int col = lane & 15;
  int kq = (lane >> 4) * 8;

  bf16x8 bfrag[6][4];  // 96 VGPRs, loaded once, L2-hot
#pragma unroll
  for (int ks = 0; ks < 6; ++ks)
#pragma unroll
    for (int nc = 0; nc < 4; ++nc)
      bfrag[ks][nc] = *(const bf16x8*)(Mb + (nc * 16 + col) * 192 + ks * 32 + kq);

  float bv[4];
#pragma unroll
  for (int nc = 0; nc < 4; ++nc) bv[nc] = bias[nc * 16 + col];

  int tbase = blockIdx.x * 8 + (t >> 6) * 2;
#pragma unroll
  for (int tt = 0; tt < 2; ++tt) {
    int tile = tbase + tt;
    if (tile >= ntiles) continue;
    int nb = tile * 16;
    int arow = nb + col;
    if (arow >= n) arow = n - 1;  // clamp (stores guarded)

    f32x4 acc[4] = {f32x4{0,0,0,0}, f32x4{0,0,0,0}, f32x4{0,0,0,0}, f32x4{0,0,0,0}};
#pragma unroll
    for (int ks = 0; ks < 6; ++ks) {
      const unsigned short* base = (ks < 2) ? Sb : (ks < 4) ? Ab : Xb;
      bf16x8 afrag = *(const bf16x8*)(base + (size_t)arow * CH + (ks & 1) * 32 + kq);
#pragma unroll
      for (int nc = 0; nc < 4; ++nc)
        acc[nc] = __builtin_amdgcn_mfma_f32_16x16x32_bf16(afrag, bfrag[ks][nc],
                                                          acc[nc], 0, 0, 0);
    }
    // C/D: col = lane&15, row = (lane>>4)*4 + reg  [m89-verified]
    int rbase = (lane >> 4) * 4;
#pragma unroll
    for (int nc = 0; nc < 4; ++nc) {
#pragma unroll
      for (int r = 0; r < 4; ++r) {
        int node = nb + rbase + r;
        if (node < n)
          out[(size_t)node * CH + nc * 16 + col] = fmaxf(acc[nc][r] + bv[nc], 0.0f);
      }
    }
  }
}

extern "C" void kernel_launch(void* const* d_in, const int* in_sizes, int n_in,
                              void* d_out, int out_size, void* d_ws, size_t ws_size,
                              hipStream_t stream) {
  const float* x    = (const float*)d_in[0];
  const int*   ei   = (const int*)d_in[1];
  const float* attr = (const float*)d_in[2];
  const float* W    = (const float*)d_in[3];
  const float* root = (const float*)d_in[4];
  const float* bias = (const float*)d_in[5];
  float* out = (float*)d_out;

  int n = in_sizes[0] / CH;   // 100000
  int E = in_sizes[2];        // 1200000
  int total = n * CH;
  int ntiles = (n + 15) / 16;
  int gemm_blocks = (ntiles + 7) / 8;
  int nbins = (n + BINSZ - 1) / BINSZ;

  size_t MbB  = ((192 * 64 * 2) + 255) & ~(size_t)255;            // 24.6KB
  size_t cntB = (((size_t)nbins * NSUB * 4) + 255) & ~(size_t)255; // 33.3KB
  size_t recB = (size_t)nbins * NSUB * SUBCAP * 8;                 // ~17.1MB
  size_t sbB  = (size_t)n * CH * 2;                                // 12.8MB each
  size_t need_main = MbB + cntB + recB + 3 * sbB;

  if (ws_size >= need_main) {
    unsigned short* Mb = (unsigned short*)d_ws;
    int*   cnt8 = (int*)((char*)d_ws + MbB);
    uint2* rec  = (uint2*)((char*)d_ws + MbB + cntB);
    unsigned short* Sb = (unsigned short*)((char*)d_ws + MbB + cntB + recB);
    unsigned short* Ab = Sb + (size_t)n * CH;
    unsigned short* xb = Ab + (size_t)n * CH;

    build_M<<<48, 256, 0, stream>>>(W, root, Mb);
    hipMemsetAsync(cnt8, 0, (size_t)nbins * NSUB * 4, stream);
    int castBlocks = (total / 8 + 255) / 256;
    int edgeBlocks = (E + 255) / 256;
    partition_cast<<<castBlocks + edgeBlocks, 256, 0, stream>>>(
        x, xb, total, castBlocks, ei, attr, cnt8, rec, E);
    gather_sort<<<nbins, 256, 0, stream>>>(xb, cnt8, rec, Sb, Ab, n);
    spline_gemm_mfma<<<gemm_blocks, 256, 0, stream>>>(Sb, Ab, xb, Mb, bias, out,
                                                      n, ntiles);
  } else {
    size_t fS = (size_t)n * CH * 4;
    unsigned short* Mb = (unsigned short*)d_ws;
    float* S    = (float*)((char*)d_ws + MbB);
    float* A1   = S + (size_t)n * CH;
    float* degf = A1 + (size_t)n * CH;
    unsigned short* Sb = (unsigned short*)((char*)(degf + n) + 256);
    unsigned short* Ab = Sb + (size_t)n * CH;
    unsigned short* xb = Ab + (size_t)n * CH;

    build_M<<<48, 256, 0, stream>>>(W, root, Mb);
    cast_x<<<(total / 8 + 255) / 256, 256, 0, stream>>>(x, xb, total);
    hipMemsetAsync(S, 0, 2 * fS + (size_t)n * 4, stream);
    spline_scatter<<<(E + 3) / 4, 256, 0, stream>>>(x, ei, attr, S, A1, degf, E);
    conv_fb<<<(total + 255) / 256, 256, 0, stream>>>(S, A1, degf, Sb, Ab, total);
    spline_gemm_mfma<<<gemm_blocks, 256, 0, stream>>>(Sb, Ab, xb, Mb, bias, out,
                                                      n, ntiles);
  }
}

// Round 9
// 204.216 us; speedup vs baseline: 1.3260x; 1.3260x over previous
//
#include <hip/hip_runtime.h>
#include <hip/hip_bf16.h>

// SplineConv K=2:  out = relu( (S/deg)@W0 + (A1/deg)@(W1-W0) + x@root + bias )
// S[n] = sum_{e->n} x[src_e],  A1[n] = sum_{e->n} v_e x[src_e].
//
// R2: f32-atomic scatter = TCC atomic-ALU bound (541us).
// R3: 2-node f32 gemm spilled (VGPR 256, 2610us).
// R4: 301us = fill 92 + gather 92 + gemm_q 90.
// R5/R7: 244us; fill 88us: scattered-LINE-transaction bound.
// R8: 271us REGRESSION. XCD sub-cursors didn't merge lines (WRITE 72->62MB
//     only): lanes still hit 64 random lines per store instruction.
// R9: LDS-staged counting-sort partition with COALESCED run writes (full
//     lines, ~300K line touches vs 1.5M), contiguous per-bin regions; K2
//     gather reads one range, 512thr/block. gemm unchanged (need counters).

#define CH 64
#define BINSZ 96     // nodes per bin
#define CAPB 2048    // records per bin region (mean 1152, ~26 sigma)
#define EPB 8192     // edges per partition block
#define K1T 512
#define MAXBINS 1280

typedef __attribute__((ext_vector_type(8))) short bf16x8;
typedef __attribute__((ext_vector_type(4))) float f32x4;
typedef __attribute__((ext_vector_type(8))) unsigned short u16x8;

static __device__ __forceinline__ unsigned short f2bu(float f) {
  __hip_bfloat16 h = __float2bfloat16(f);  // RTN
  return *(unsigned short*)&h;
}
static __device__ __forceinline__ float bu2f(unsigned short u) {
  return __uint_as_float(((unsigned)u) << 16);
}

// ---------- combined weight M^T bf16 [64][192] ----------
__global__ __launch_bounds__(256) void build_M(
    const float* __restrict__ W, const float* __restrict__ root,
    unsigned short* __restrict__ Mb) {
  int idx = blockIdx.x * 256 + threadIdx.x;
  if (idx >= 192 * 64) return;
  int k = idx >> 6, o = idx & 63;
  float val;
  if (k < 64)       val = W[k * 64 + o];
  else if (k < 128) val = W[4096 + (k - 64) * 64 + o] - W[(k - 64) * 64 + o];
  else              val = root[(k - 128) * 64 + o];
  Mb[o * 192 + k] = f2bu(val);
}

// ---------- cast x (f32) -> xb (bf16) ----------
__global__ __launch_bounds__(256) void cast_x(
    const float* __restrict__ x, unsigned short* __restrict__ xb, int total) {
  int i = (blockIdx.x * 256 + threadIdx.x) * 8;
  if (i >= total) return;
  const float4* p = (const float4*)(x + i);
  float4 a = p[0], b = p[1];
  u16x8 o;
  o[0] = f2bu(a.x); o[1] = f2bu(a.y); o[2] = f2bu(a.z); o[3] = f2bu(a.w);
  o[4] = f2bu(b.x); o[5] = f2bu(b.y); o[6] = f2bu(b.z); o[7] = f2bu(b.w);
  *(u16x8*)(xb + i) = o;
}

// ---------- K1: LDS counting-sort partition, coalesced run writes ----------
__global__ __launch_bounds__(K1T) void partition_sort(
    const int* __restrict__ ei, const float* __restrict__ attr,
    int* __restrict__ gcnt, uint2* __restrict__ rec, int E, int nbins) {
  __shared__ uint2 lrec[EPB];                 // 64KB
  __shared__ unsigned short sidx[EPB];        // 16KB
  __shared__ int hist[MAXBINS], off[MAXBINS], cur[MAXBINS], gbase[MAXBINS];
  __shared__ int partial[K1T], scan[K1T];
  int t = threadIdx.x;
  int start = blockIdx.x * EPB;
  int len = E - start; if (len > EPB) len = EPB;

  for (int b = t; b < nbins; b += K1T) hist[b] = 0;
  __syncthreads();

  // stage + histogram (coalesced global reads)
  for (int i = t; i < len; i += K1T) {
    int e = start + i;
    int src = ei[e], dst = ei[E + e];
    float v = attr[e];
    unsigned enc = ((unsigned)src << 15) | (unsigned)(v * 32767.0f + 0.5f);
    lrec[i] = make_uint2(enc, (unsigned)dst);
    atomicAdd(&hist[(unsigned)dst / BINSZ], 1);
  }
  __syncthreads();

  // parallel exclusive scan of hist -> off (Hillis-Steele over thread sums)
  int bpt = (nbins + K1T - 1) / K1T;
  int b0 = t * bpt;
  int psum = 0;
  for (int b = b0; b < b0 + bpt && b < nbins; ++b) psum += hist[b];
  partial[t] = psum; scan[t] = psum;
  __syncthreads();
  for (int d = 1; d < K1T; d <<= 1) {
    int v2 = (t >= d) ? scan[t - d] : 0;
    __syncthreads();
    scan[t] += v2;
    __syncthreads();
  }
  int run = scan[t] - partial[t];
  for (int b = b0; b < b0 + bpt && b < nbins; ++b) {
    off[b] = run; cur[b] = run; run += hist[b];
    if (hist[b] > 0) gbase[b] = atomicAdd(&gcnt[b], hist[b]);  // reserve range
  }
  __syncthreads();

  // rank-scatter: sorted position of each staged record
  for (int i = t; i < len; i += K1T) {
    int p = atomicAdd(&cur[lrec[i].y / BINSZ], 1);
    sidx[p] = (unsigned short)i;
  }
  __syncthreads();

  // coalesced writes: sorted index i -> contiguous slot in bin's region
  for (int i = t; i < len; i += K1T) {
    uint2 r = lrec[sidx[i]];
    unsigned bin = r.y / BINSZ;
    int gpos = gbase[bin] + (i - off[bin]);
    if (gpos < CAPB)
      rec[(size_t)bin * CAPB + gpos] = make_uint2(r.x, r.y - bin * BINSZ);
  }
}

// ---------- K2: per-bin LDS sort + register gather ----------
__global__ __launch_bounds__(512) void gather_bin(
    const unsigned short* __restrict__ xb, const int* __restrict__ gcnt,
    const uint2* __restrict__ rec, unsigned short* __restrict__ Sb,
    unsigned short* __restrict__ Ab, int n) {
  __shared__ uint2 lrec[CAPB];           // 16KB
  __shared__ unsigned short sidx[CAPB];  // 4KB
  __shared__ int hist[BINSZ], off[BINSZ], cur[BINSZ];
  int bin = blockIdx.x, t = threadIdx.x;
  int tot = gcnt[bin]; if (tot > CAPB) tot = CAPB;
  for (int i = t; i < BINSZ; i += 512) hist[i] = 0;
  __syncthreads();
  for (int i = t; i < tot; i += 512) {   // contiguous, coalesced
    uint2 r = rec[(size_t)bin * CAPB + i];
    lrec[i] = r;
    atomicAdd(&hist[r.y], 1);
  }
  __syncthreads();
  if (t == 0) {
    int s = 0;
    for (int d = 0; d < BINSZ; ++d) { off[d] = s; cur[d] = s; s += hist[d]; }
  }
  __syncthreads();
  for (int i = t; i < tot; i += 512) {
    int p = atomicAdd(&cur[lrec[i].y], 1);
    sidx[p] = (unsigned short)i;
  }
  __syncthreads();

  int wv = t >> 6, lane = t & 63;
  int nlocal = n - bin * BINSZ;
  if (nlocal > BINSZ) nlocal = BINSZ;
  for (int d = wv; d < nlocal; d += 8) {
    int deg = hist[d], base = off[d];
    float s = 0.0f, a = 0.0f;
    for (int j = 0; j < deg; j += 16) {
      unsigned short xr[16];
      unsigned ee[16];
#pragma unroll
      for (int u = 0; u < 16; ++u) {
        int jj = j + u;
        bool val = jj < deg;                    // wave-uniform
        int idx = base + (val ? jj : 0);
        unsigned e = lrec[sidx[idx]].x;         // LDS broadcast
        ee[u] = val ? e : 0u;
        int srcj = val ? (int)(e >> 15) : 0;
        xr[u] = xb[(size_t)srcj * CH + lane];   // 16 independent 128B gathers
      }
#pragma unroll
      for (int u = 0; u < 16; ++u) {
        float w = (j + u < deg) ? 1.0f : 0.0f;
        float xv = bu2f(xr[u]);
        float vv = (float)(ee[u] & 32767u) * (1.0f / 32767.0f);
        s = fmaf(w, xv, s);
        a = fmaf(w * vv, xv, a);
      }
    }
    int node = bin * BINSZ + d;
    float inv = 1.0f / fmaxf((float)deg, 1.0f);  // fold mean
    Sb[(size_t)node * CH + lane] = f2bu(s * inv);
    Ab[(size_t)node * CH + lane] = f2bu(a * inv);
  }
}

// ---------- fallback path (ws too small): atomic scatter ----------
__global__ __launch_bounds__(256) void spline_scatter(
    const float* __restrict__ x, const int* __restrict__ ei,
    const float* __restrict__ attr, float* __restrict__ S,
    float* __restrict__ A1, float* __restrict__ degf, int E) {
  int w = (int)((blockIdx.x * 4) + (threadIdx.x >> 6));
  int lane = threadIdx.x & 63;
  if (w >= E) return;
  int src = ei[w];
  int dst = ei[E + w];
  float v = attr[w];
  float xv = x[(size_t)src * CH + lane];
  atomicAdd(&S[(size_t)dst * CH + lane], xv);
  atomicAdd(&A1[(size_t)dst * CH + lane], v * xv);
  if (lane == 0) atomicAdd(&degf[dst], 1.0f);
}

__global__ __launch_bounds__(256) void conv_fb(
    const float* __restrict__ S, const float* __restrict__ A1,
    const float* __restrict__ degf, unsigned short* __restrict__ Sb,
    unsigned short* __restrict__ Ab, int total) {
  int i = blockIdx.x * 256 + threadIdx.x;
  if (i >= total) return;
  float inv = 1.0f / fmaxf(degf[i >> 6], 1.0f);
  Sb[i] = f2bu(S[i] * inv);
  Ab[i] = f2bu(A1[i] * inv);
}

// ---------- MFMA GEMM: B-frags in regs, 2 tiles/wave, no LDS ----------
__global__ __launch_bounds__(256) void spline_gemm_mfma(
    const unsigned short* __restrict__ Sb, const unsigned short* __restrict__ Ab,
    const unsigned short* __restrict__ Xb, const unsigned short* __restrict__ Mb,
    const float* __restrict__ bias, float* __restrict__ out, int n, int ntiles) {
  int t = threadIdx.x;
  int lane = t & 63;
  int col = lane & 15;
  int kq = (lane >> 4) * 8;

  bf16x8 bfrag[6][4];  // 96 VGPRs, loaded once, L2-hot
#pragma unroll
  for (int ks = 0; ks < 6; ++ks)
#pragma unroll
    for (int nc = 0; nc < 4; ++nc)
      bfrag[ks][nc] = *(const bf16x8*)(Mb + (nc * 16 + col) * 192 + ks * 32 + kq);

  float bv[4];
#pragma unroll
  for (int nc = 0; nc < 4; ++nc) bv[nc] = bias[nc * 16 + col];

  int tbase = blockIdx.x * 8 + (t >> 6) * 2;
#pragma unroll
  for (int tt = 0; tt < 2; ++tt) {
    int tile = tbase + tt;
    if (tile >= ntiles) continue;
    int nb = tile * 16;
    int arow = nb + col;
    if (arow >= n) arow = n - 1;  // clamp (stores guarded)

    f32x4 acc[4] = {f32x4{0,0,0,0}, f32x4{0,0,0,0}, f32x4{0,0,0,0}, f32x4{0,0,0,0}};
#pragma unroll
    for (int ks = 0; ks < 6; ++ks) {
      const unsigned short* base = (ks < 2) ? Sb : (ks < 4) ? Ab : Xb;
      bf16x8 afrag = *(const bf16x8*)(base + (size_t)arow * CH + (ks & 1) * 32 + kq);
#pragma unroll
      for (int nc = 0; nc < 4; ++nc)
        acc[nc] = __builtin_amdgcn_mfma_f32_16x16x32_bf16(afrag, bfrag[ks][nc],
                                                          acc[nc], 0, 0, 0);
    }
    // C/D: col = lane&15, row = (lane>>4)*4 + reg  [m89-verified]
    int rbase = (lane >> 4) * 4;
#pragma unroll
    for (int nc = 0; nc < 4; ++nc) {
#pragma unroll
      for (int r = 0; r < 4; ++r) {
        int node = nb + rbase + r;
        if (node < n)
          out[(size_t)node * CH + nc * 16 + col] = fmaxf(acc[nc][r] + bv[nc], 0.0f);
      }
    }
  }
}

extern "C" void kernel_launch(void* const* d_in, const int* in_sizes, int n_in,
                              void* d_out, int out_size, void* d_ws, size_t ws_size,
                              hipStream_t stream) {
  const float* x    = (const float*)d_in[0];
  const int*   ei   = (const int*)d_in[1];
  const float* attr = (const float*)d_in[2];
  const float* W    = (const float*)d_in[3];
  const float* root = (const float*)d_in[4];
  const float* bias = (const float*)d_in[5];
  float* out = (float*)d_out;

  int n = in_sizes[0] / CH;   // 100000
  int E = in_sizes[2];        // 1200000
  int total = n * CH;
  int ntiles = (n + 15) / 16;
  int gemm_blocks = (ntiles + 7) / 8;
  int nbins = (n + BINSZ - 1) / BINSZ;   // 1042

  size_t MbB  = ((192 * 64 * 2) + 255) & ~(size_t)255;             // 24.6KB
  size_t cntB = (((size_t)nbins * 4) + 255) & ~(size_t)255;
  size_t recB = (size_t)nbins * CAPB * 8;                          // ~17.1MB
  size_t sbB  = (size_t)n * CH * 2;                                // 12.8MB each
  size_t need_main = MbB + cntB + recB + 3 * sbB;

  if (nbins <= MAXBINS && ws_size >= need_main) {
    unsigned short* Mb = (unsigned short*)d_ws;
    int*   gcnt = (int*)((char*)d_ws + MbB);
    uint2* rec  = (uint2*)((char*)d_ws + MbB + cntB);
    unsigned short* Sb = (unsigned short*)((char*)d_ws + MbB + cntB + recB);
    unsigned short* Ab = Sb + (size_t)n * CH;
    unsigned short* xb = Ab + (size_t)n * CH;

    build_M<<<48, 256, 0, stream>>>(W, root, Mb);
    cast_x<<<(total / 8 + 255) / 256, 256, 0, stream>>>(x, xb, total);
    hipMemsetAsync(gcnt, 0, (size_t)nbins * 4, stream);
    partition_sort<<<(E + EPB - 1) / EPB, K1T, 0, stream>>>(ei, attr, gcnt, rec,
                                                            E, nbins);
    gather_bin<<<nbins, 512, 0, stream>>>(xb, gcnt, rec, Sb, Ab, n);
    spline_gemm_mfma<<<gemm_blocks, 256, 0, stream>>>(Sb, Ab, xb, Mb, bias, out,
                                                      n, ntiles);
  } else {
    size_t fS = (size_t)n * CH * 4;
    unsigned short* Mb = (unsigned short*)d_ws;
    float* S    = (float*)((char*)d_ws + MbB);
    float* A1   = S + (size_t)n * CH;
    float* degf = A1 + (size_t)n * CH;
    unsigned short* Sb = (unsigned short*)((char*)(degf + n) + 256);
    unsigned short* Ab = Sb + (size_t)n * CH;
    unsigned short* xb = Ab + (size_t)n * CH;

    build_M<<<48, 256, 0, stream>>>(W, root, Mb);
    cast_x<<<(total / 8 + 255) / 256, 256, 0, stream>>>(x, xb, total);
    hipMemsetAsync(S, 0, 2 * fS + (size_t)n * 4, stream);
    spline_scatter<<<(E + 3) / 4, 256, 0, stream>>>(x, ei, attr, S, A1, degf, E);
    conv_fb<<<(total + 255) / 256, 256, 0, stream>>>(S, A1, degf, Sb, Ab, total);
    spline_gemm_mfma<<<gemm_blocks, 256, 0, stream>>>(Sb, Ab, xb, Mb, bias, out,
                                                      n, ntiles);
  }
}

// Round 11
// 183.369 us; speedup vs baseline: 1.4767x; 1.1137x over previous
//
#include <hip/hip_runtime.h>
#include <hip/hip_bf16.h>

// SplineConv K=2:  out = relu( (S/deg)@W0 + (A1/deg)@(W1-W0) + x@root + bias )
// S[n] = sum_{e->n} x[src_e],  A1[n] = sum_{e->n} v_e x[src_e].
//
// R2: f32-atomic scatter = TCC atomic-ALU bound (541us).
// R4: 301us; R5/R7: 244us (fill line-transaction bound ~88us).
// R8: 271us REGRESSION (XCD sub-cursors don't merge scattered lines).
// R9: 204us. partition_sort + gather_bin (sorted bins, coalesced runs).
//     gather_bin 69us @ VALUBusy 77% = VALU-inst bound (~12 inst/edge-lane);
//     partition_sort hidden ~60-90us (147 blocks = 57% of CUs, 18-barrier scan).
// R10/R11: gather: physical LDS reorder (no sidx), f32 v in record (no decode),
//     unmasked 8-chunks + masked tail (~7 inst/edge-lane).
//     partition: EPB 4096 / 293 blocks (2/CU), shfl wave-scan (2 barriers).
//     (R10 bench was an infra failure; resubmitted unchanged.)

#define CH 64
#define BINSZ 96     // nodes per bin
#define CAPB 2048    // records per bin region (mean 1152, ~26 sigma)
#define EPB 4096     // edges per partition block
#define K1T 512
#define MAXBINS 1280

typedef __attribute__((ext_vector_type(8))) short bf16x8;
typedef __attribute__((ext_vector_type(4))) float f32x4;
typedef __attribute__((ext_vector_type(8))) unsigned short u16x8;

static __device__ __forceinline__ unsigned short f2bu(float f) {
  __hip_bfloat16 h = __float2bfloat16(f);  // RTN
  return *(unsigned short*)&h;
}
static __device__ __forceinline__ float bu2f(unsigned short u) {
  return __uint_as_float(((unsigned)u) << 16);
}

// ---------- combined weight M^T bf16 [64][192] ----------
__global__ __launch_bounds__(256) void build_M(
    const float* __restrict__ W, const float* __restrict__ root,
    unsigned short* __restrict__ Mb) {
  int idx = blockIdx.x * 256 + threadIdx.x;
  if (idx >= 192 * 64) return;
  int k = idx >> 6, o = idx & 63;
  float val;
  if (k < 64)       val = W[k * 64 + o];
  else if (k < 128) val = W[4096 + (k - 64) * 64 + o] - W[(k - 64) * 64 + o];
  else              val = root[(k - 128) * 64 + o];
  Mb[o * 192 + k] = f2bu(val);
}

// ---------- cast x (f32) -> xb (bf16) ----------
__global__ __launch_bounds__(256) void cast_x(
    const float* __restrict__ x, unsigned short* __restrict__ xb, int total) {
  int i = (blockIdx.x * 256 + threadIdx.x) * 8;
  if (i >= total) return;
  const float4* p = (const float4*)(x + i);
  float4 a = p[0], b = p[1];
  u16x8 o;
  o[0] = f2bu(a.x); o[1] = f2bu(a.y); o[2] = f2bu(a.z); o[3] = f2bu(a.w);
  o[4] = f2bu(b.x); o[5] = f2bu(b.y); o[6] = f2bu(b.z); o[7] = f2bu(b.w);
  *(u16x8*)(xb + i) = o;
}

// ---------- K1: LDS counting-sort partition, coalesced run writes ----------
// record: .x = src<<7 | dloc (24b), .y = v as f32
__global__ __launch_bounds__(K1T) void partition_sort(
    const int* __restrict__ ei, const float* __restrict__ attr,
    int* __restrict__ gcnt, uint2* __restrict__ rec, int E, int nbins) {
  __shared__ uint2 lrec[EPB];                  // 32KB
  __shared__ unsigned short lbin[EPB];         // 8KB
  __shared__ unsigned short sidx[EPB];         // 8KB
  __shared__ int hist[MAXBINS], off[MAXBINS], cur[MAXBINS], gbase[MAXBINS];
  __shared__ int wsum[8];
  int t = threadIdx.x;
  int lane = t & 63, wid = t >> 6;
  int start = blockIdx.x * EPB;
  int len = E - start; if (len > EPB) len = EPB;

  for (int b = t; b < nbins; b += K1T) hist[b] = 0;
  __syncthreads();

  // stage + histogram (coalesced global reads)
  for (int i = t; i < len; i += K1T) {
    int e = start + i;
    unsigned src = (unsigned)ei[e];
    unsigned dst = (unsigned)ei[E + e];
    float v = attr[e];
    unsigned bin = dst / BINSZ;
    unsigned dloc = dst - bin * BINSZ;
    lrec[i] = make_uint2((src << 7) | dloc, __float_as_uint(v));
    lbin[i] = (unsigned short)bin;
    atomicAdd(&hist[bin], 1);
  }
  __syncthreads();

  // exclusive scan of hist: per-thread sum -> shfl wave-scan -> wave combine
  int bpt = (nbins + K1T - 1) / K1T;
  int b0 = t * bpt;
  int psum = 0;
  for (int b = b0; b < b0 + bpt && b < nbins; ++b) psum += hist[b];
  int sc = psum;
#pragma unroll
  for (int d = 1; d < 64; d <<= 1) {
    int v2 = __shfl_up(sc, d);
    if (lane >= d) sc += v2;
  }
  if (lane == 63) wsum[wid] = sc;
  __syncthreads();
  int run = sc - psum;
  for (int k = 0; k < wid; ++k) run += wsum[k];
  for (int b = b0; b < b0 + bpt && b < nbins; ++b) {
    off[b] = run; cur[b] = run;
    int h = hist[b];
    if (h > 0) gbase[b] = atomicAdd(&gcnt[b], h);  // reserve global range
    run += h;
  }
  __syncthreads();

  // rank-scatter: sorted position of each staged record
  for (int i = t; i < len; i += K1T) {
    int p = atomicAdd(&cur[lbin[i]], 1);
    sidx[p] = (unsigned short)i;
  }
  __syncthreads();

  // coalesced writes: sorted slot i -> contiguous position in bin's region
  for (int i = t; i < len; i += K1T) {
    int s = sidx[i];
    uint2 r = lrec[s];
    unsigned bin = lbin[s];
    int gpos = gbase[bin] + (i - off[bin]);
    if (gpos < CAPB) rec[(size_t)bin * CAPB + gpos] = r;
  }
}

// ---------- K2: per-bin LDS sort (physical reorder) + register gather ----------
__global__ __launch_bounds__(512) void gather_bin(
    const unsigned short* __restrict__ xb, const int* __restrict__ gcnt,
    const uint2* __restrict__ rec, unsigned short* __restrict__ Sb,
    unsigned short* __restrict__ Ab, int n) {
  __shared__ uint2 lrec[CAPB];   // 16KB staging
  __shared__ uint2 lsort[CAPB];  // 16KB sorted by node
  __shared__ int hist[BINSZ], off[BINSZ], cur[BINSZ];
  int bin = blockIdx.x, t = threadIdx.x;
  int tot = gcnt[bin]; if (tot > CAPB) tot = CAPB;
  for (int i = t; i < BINSZ; i += 512) hist[i] = 0;
  __syncthreads();
  for (int i = t; i < tot; i += 512) {   // contiguous, coalesced
    uint2 r = rec[(size_t)bin * CAPB + i];
    lrec[i] = r;
    atomicAdd(&hist[r.x & 127], 1);
  }
  __syncthreads();
  if (t == 0) {
    int s = 0;
    for (int d = 0; d < BINSZ; ++d) { off[d] = s; cur[d] = s; s += hist[d]; }
  }
  __syncthreads();
  for (int i = t; i < tot; i += 512) {   // physical reorder
    uint2 r = lrec[i];
    int p = atomicAdd(&cur[r.x & 127], 1);
    lsort[p] = r;
  }
  __syncthreads();

  int wv = t >> 6, lane = t & 63;
  int nlocal = n - bin * BINSZ;
  if (nlocal > BINSZ) nlocal = BINSZ;
  for (int d = wv; d < nlocal; d += 8) {
    int deg = hist[d], base = off[d];
    float s = 0.0f, a = 0.0f;
    int j = 0;
    for (; j + 8 <= deg; j += 8) {       // unmasked main chunks
      unsigned short xr[8];
      float vv[8];
#pragma unroll
      for (int u = 0; u < 8; ++u) {
        uint2 r = lsort[base + j + u];   // broadcast ds_read_b64
        vv[u] = __uint_as_float(r.y);
        xr[u] = xb[(size_t)(r.x >> 7) * CH + lane];  // 8 gathers in flight
      }
#pragma unroll
      for (int u = 0; u < 8; ++u) {
        float xv = bu2f(xr[u]);
        s += xv;
        a = fmaf(vv[u], xv, a);
      }
    }
    int rem = deg - j;
    if (rem) {                           // one masked tail (<=7 slots)
      unsigned short xr[8];
      float vv[8], w[8];
#pragma unroll
      for (int u = 0; u < 8; ++u) {
        bool val = u < rem;              // wave-uniform
        uint2 r = lsort[base + j + (val ? u : 0)];
        w[u] = val ? 1.0f : 0.0f;
        vv[u] = __uint_as_float(r.y);
        xr[u] = xb[(size_t)(r.x >> 7) * CH + lane];
      }
#pragma unroll
      for (int u = 0; u < 8; ++u) {
        float xv = bu2f(xr[u]);
        s = fmaf(w[u], xv, s);
        a = fmaf(w[u] * vv[u], xv, a);
      }
    }
    int node = bin * BINSZ + d;
    float inv = 1.0f / fmaxf((float)deg, 1.0f);  // fold mean
    Sb[(size_t)node * CH + lane] = f2bu(s * inv);
    Ab[(size_t)node * CH + lane] = f2bu(a * inv);
  }
}

// ---------- fallback path (ws too small): atomic scatter ----------
__global__ __launch_bounds__(256) void spline_scatter(
    const float* __restrict__ x, const int* __restrict__ ei,
    const float* __restrict__ attr, float* __restrict__ S,
    float* __restrict__ A1, float* __restrict__ degf, int E) {
  int w = (int)((blockIdx.x * 4) + (threadIdx.x >> 6));
  int lane = threadIdx.x & 63;
  if (w >= E) return;
  int src = ei[w];
  int dst = ei[E + w];
  float v = attr[w];
  float xv = x[(size_t)src * CH + lane];
  atomicAdd(&S[(size_t)dst * CH + lane], xv);
  atomicAdd(&A1[(size_t)dst * CH + lane], v * xv);
  if (lane == 0) atomicAdd(&degf[dst], 1.0f);
}

__global__ __launch_bounds__(256) void conv_fb(
    const float* __restrict__ S, const float* __restrict__ A1,
    const float* __restrict__ degf, unsigned short* __restrict__ Sb,
    unsigned short* __restrict__ Ab, int total) {
  int i = blockIdx.x * 256 + threadIdx.x;
  if (i >= total) return;
  float inv = 1.0f / fmaxf(degf[i >> 6], 1.0f);
  Sb[i] = f2bu(S[i] * inv);
  Ab[i] = f2bu(A1[i] * inv);
}

// ---------- MFMA GEMM: B-frags in regs, 2 tiles/wave, no LDS ----------
__global__ __launch_bounds__(256) void spline_gemm_mfma(
    const unsigned short* __restrict__ Sb, const unsigned short* __restrict__ Ab,
    const unsigned short* __restrict__ Xb, const unsigned short* __restrict__ Mb,
    const float* __restrict__ bias, float* __restrict__ out, int n, int ntiles) {
  int t = threadIdx.x;
  int lane = t & 63;
  int col = lane & 15;
  int kq = (lane >> 4) * 8;

  bf16x8 bfrag[6][4];  // 96 VGPRs, loaded once, L2-hot
#pragma unroll
  for (int ks = 0; ks < 6; ++ks)
#pragma unroll
    for (int nc = 0; nc < 4; ++nc)
      bfrag[ks][nc] = *(const bf16x8*)(Mb + (nc * 16 + col) * 192 + ks * 32 + kq);

  float bv[4];
#pragma unroll
  for (int nc = 0; nc < 4; ++nc) bv[nc] = bias[nc * 16 + col];

  int tbase = blockIdx.x * 8 + (t >> 6) * 2;
#pragma unroll
  for (int tt = 0; tt < 2; ++tt) {
    int tile = tbase + tt;
    if (tile >= ntiles) continue;
    int nb = tile * 16;
    int arow = nb + col;
    if (arow >= n) arow = n - 1;  // clamp (stores guarded)

    f32x4 acc[4] = {f32x4{0,0,0,0}, f32x4{0,0,0,0}, f32x4{0,0,0,0}, f32x4{0,0,0,0}};
#pragma unroll
    for (int ks = 0; ks < 6; ++ks) {
      const unsigned short* base = (ks < 2) ? Sb : (ks < 4) ? Ab : Xb;
      bf16x8 afrag = *(const bf16x8*)(base + (size_t)arow * CH + (ks & 1) * 32 + kq);
#pragma unroll
      for (int nc = 0; nc < 4; ++nc)
        acc[nc] = __builtin_amdgcn_mfma_f32_16x16x32_bf16(afrag, bfrag[ks][nc],
                                                          acc[nc], 0, 0, 0);
    }
    // C/D: col = lane&15, row = (lane>>4)*4 + reg  [m89-verified]
    int rbase = (lane >> 4) * 4;
#pragma unroll
    for (int nc = 0; nc < 4; ++nc) {
#pragma unroll
      for (int r = 0; r < 4; ++r) {
        int node = nb + rbase + r;
        if (node < n)
          out[(size_t)node * CH + nc * 16 + col] = fmaxf(acc[nc][r] + bv[nc], 0.0f);
      }
    }
  }
}

extern "C" void kernel_launch(void* const* d_in, const int* in_sizes, int n_in,
                              void* d_out, int out_size, void* d_ws, size_t ws_size,
                              hipStream_t stream) {
  const float* x    = (const float*)d_in[0];
  const int*   ei   = (const int*)d_in[1];
  const float* attr = (const float*)d_in[2];
  const float* W    = (const float*)d_in[3];
  const float* root = (const float*)d_in[4];
  const float* bias = (const float*)d_in[5];
  float* out = (float*)d_out;

  int n = in_sizes[0] / CH;   // 100000
  int E = in_sizes[2];        // 1200000
  int total = n * CH;
  int ntiles = (n + 15) / 16;
  int gemm_blocks = (ntiles + 7) / 8;
  int nbins = (n + BINSZ - 1) / BINSZ;   // 1042

  size_t MbB  = ((192 * 64 * 2) + 255) & ~(size_t)255;             // 24.6KB
  size_t cntB = (((size_t)nbins * 4) + 255) & ~(size_t)255;
  size_t recB = (size_t)nbins * CAPB * 8;                          // ~17.1MB
  size_t sbB  = (size_t)n * CH * 2;                                // 12.8MB each
  size_t need_main = MbB + cntB + recB + 3 * sbB;

  if (nbins <= MAXBINS && ws_size >= need_main) {
    unsigned short* Mb = (unsigned short*)d_ws;
    int*   gcnt = (int*)((char*)d_ws + MbB);
    uint2* rec  = (uint2*)((char*)d_ws + MbB + cntB);
    unsigned short* Sb = (unsigned short*)((char*)d_ws + MbB + cntB + recB);
    unsigned short* Ab = Sb + (size_t)n * CH;
    unsigned short* xb = Ab + (size_t)n * CH;

    build_M<<<48, 256, 0, stream>>>(W, root, Mb);
    cast_x<<<(total / 8 + 255) / 256, 256, 0, stream>>>(x, xb, total);
    hipMemsetAsync(gcnt, 0, (size_t)nbins * 4, stream);
    partition_sort<<<(E + EPB - 1) / EPB, K1T, 0, stream>>>(ei, attr, gcnt, rec,
                                                            E, nbins);
    gather_bin<<<nbins, 512, 0, stream>>>(xb, gcnt, rec, Sb, Ab, n);
    spline_gemm_mfma<<<gemm_blocks, 256, 0, stream>>>(Sb, Ab, xb, Mb, bias, out,
                                                      n, ntiles);
  } else {
    size_t fS = (size_t)n * CH * 4;
    unsigned short* Mb = (unsigned short*)d_ws;
    float* S    = (float*)((char*)d_ws + MbB);
    float* A1   = S + (size_t)n * CH;
    float* degf = A1 + (size_t)n * CH;
    unsigned short* Sb = (unsigned short*)((char*)(degf + n) + 256);
    unsigned short* Ab = Sb + (size_t)n * CH;
    unsigned short* xb = Ab + (size_t)n * CH;

    build_M<<<48, 256, 0, stream>>>(W, root, Mb);
    cast_x<<<(total / 8 + 255) / 256, 256, 0, stream>>>(x, xb, total);
    hipMemsetAsync(S, 0, 2 * fS + (size_t)n * 4, stream);
    spline_scatter<<<(E + 3) / 4, 256, 0, stream>>>(x, ei, attr, S, A1, degf, E);
    conv_fb<<<(total + 255) / 256, 256, 0, stream>>>(S, A1, degf, Sb, Ab, total);
    spline_gemm_mfma<<<gemm_blocks, 256, 0, stream>>>(Sb, Ab, xb, Mb, bias, out,
                                                      n, ntiles);
  }
}